// Round 1
// 594.914 us; speedup vs baseline: 1.1635x; 1.1635x over previous
//
#include <hip/hip_runtime.h>
#include <hip/hip_bf16.h>
#include <stdint.h>

#define B_ 8
#define L_ 1024
#define H_ 768
#define E_ 16
#define W_ 504
#define DFF_ 512
#define N_ 5982
#define NE_ (N_*E_)    // 95712 candidates per batch
#define BNE_ (B_*NE_)  // 765696
#define MAXC_ 6144     // padded per-batch candidate capacity (>= N_)

typedef unsigned long long u64;
typedef unsigned int u32;

__device__ __forceinline__ int rowstart_of(int s){
    int s0 = W_ - 11; // 493
    if (s <= s0) return 12*s;
    int t = s - s0;
    return 12*s0 + t*11 - (t*(t-1))/2;
}

__device__ __forceinline__ u64 shfl_u64(u64 x, int j){
    u32 lo = (u32)__shfl((int)(u32)(x & 0xFFFFFFFFull), j, 64);
    u32 hi = (u32)__shfl((int)(u32)(x >> 32), j, 64);
    return ((u64)hi << 32) | (u64)lo;
}

// ---------------- span tables ----------------
__global__ void k_tables(int* starts, int* ends){
    int s = blockIdx.x*64 + threadIdx.x;
    if (s >= W_) return;
    int rs = rowstart_of(s);
    int cnt = min(12, W_ - s);
    for (int i = 0; i < cnt; i++){ starts[rs+i] = s; ends[rs+i] = s+i; }
}

// ---------------- token lists: parallel build + deterministic per-word sort ----------------
__global__ void k_toklist(const int* __restrict__ tm, const int* __restrict__ wi,
                          int* __restrict__ tok, int* __restrict__ tokc){
    int i = blockIdx.x*256 + threadIdx.x;
    if (i >= B_*L_) return;
    int w = wi[i];
    if (tm[i] == 1 && w >= 0 && w < W_){
        int b = i / L_;
        int bw = b*W_ + w;
        int pos = atomicAdd(&tokc[bw], 1);
        if (pos < 4) tok[bw*4 + pos] = i - b*L_;
    }
}

__global__ void k_toksort(int* __restrict__ tok, const int* __restrict__ tokc){
    int bw = blockIdx.x*256 + threadIdx.x;
    if (bw >= B_*W_) return;
    int c = min(tokc[bw], 4);
    int v[4];
    for (int k = 0; k < c; k++) v[k] = tok[bw*4 + k];
    for (int a = 1; a < c; a++){ int x = v[a]; int j = a-1; while (j >= 0 && v[j] > x){ v[j+1] = v[j]; j--; } v[j+1] = x; }
    for (int k = 0; k < c; k++) tok[bw*4 + k] = v[k];
}

// ---------------- word mean pooling (gather, deterministic) ----------------
__global__ void k_pool(const float* __restrict__ hs,
                       const int* __restrict__ tok, const int* __restrict__ tokc,
                       float* __restrict__ wemb){
    int idx = blockIdx.x*256 + threadIdx.x;      // over B*W*H
    if (idx >= B_*W_*H_) return;
    int h = idx % H_; int bw = idx / H_; int b = bw / W_;
    int c = tokc[bw]; int cc = min(c, 4);
    double s = 0.0;
    for (int k = 0; k < cc; k++){
        int l = tok[bw*4 + k];
        s += (double)hs[((size_t)(b*L_ + l))*H_ + h];
    }
    float denom = (float)max(c, 1);
    wemb[idx] = (float)(s / (double)denom);
}

// ---------------- entity positions: literal stable scan ----------------
__global__ void k_entpos(const int* __restrict__ ent_mask, int* __restrict__ ent_pos){
    int b = blockIdx.x;
    if (threadIdx.x != 0) return;
    int c = 0;
    for (int l = 0; l < L_ && c < E_; l++) if (ent_mask[b*L_ + l] == 1) ent_pos[b*E_ + c++] = l;
    for (int l = 0; l < L_ && c < E_; l++) if (ent_mask[b*L_ + l] != 1) ent_pos[b*E_ + c++] = l;
}

// ---------------- entity MLP layer 1: hidg[be,d] = leaky(x[be]·w1[:,d] + b1[d]) ----------------
__global__ void k_ent1(const float* __restrict__ hs, const int* __restrict__ ent_pos,
                       const float* __restrict__ w1, const float* __restrict__ b1,
                       float* __restrict__ hidg){
    __shared__ float x[H_];
    int blk = blockIdx.x;            // 256 blocks: be*2 + half
    int be = blk >> 1; int half = blk & 1;
    int b = be >> 4;
    int tid = threadIdx.x;
    int pos = ent_pos[be];
    const float* xp = hs + ((size_t)b*L_ + pos)*H_;
    for (int j = tid; j < H_; j += 256) x[j] = xp[j];
    __syncthreads();
    int d = half*256 + tid;
    float a0=0.f,a1=0.f,a2=0.f,a3=0.f;
    const float* wp = w1 + d;
    #pragma unroll 4
    for (int h = 0; h < H_; h += 4){
        a0 += x[h+0]*wp[(size_t)(h+0)*DFF_];
        a1 += x[h+1]*wp[(size_t)(h+1)*DFF_];
        a2 += x[h+2]*wp[(size_t)(h+2)*DFF_];
        a3 += x[h+3]*wp[(size_t)(h+3)*DFF_];
    }
    float acc = ((a0+a1)+(a2+a3)) + b1[d];
    hidg[(size_t)be*DFF_ + d] = acc > 0.f ? acc : 0.01f*acc;
}

// ---------------- entity MLP layer 2: ent_vec[be,j] = hid[be]·w2[:,j] + b2[j] ----------------
__global__ void k_ent2(const float* __restrict__ hidg,
                       const float* __restrict__ w2, const float* __restrict__ b2,
                       float* __restrict__ ent_vec){
    __shared__ float hsd[DFF_];
    int blk = blockIdx.x;            // 384 blocks: be*3 + third
    int be = blk / 3; int third = blk % 3;
    int tid = threadIdx.x;
    const float* hp = hidg + (size_t)be*DFF_;
    for (int j = tid; j < DFF_; j += 256) hsd[j] = hp[j];
    __syncthreads();
    int j = third*256 + tid;
    float a0=0.f,a1=0.f,a2=0.f,a3=0.f;
    const float* wp = w2 + j;
    #pragma unroll 4
    for (int d = 0; d < DFF_; d += 4){
        a0 += hsd[d+0]*wp[(size_t)(d+0)*H_];
        a1 += hsd[d+1]*wp[(size_t)(d+1)*H_];
        a2 += hsd[d+2]*wp[(size_t)(d+2)*H_];
        a3 += hsd[d+3]*wp[(size_t)(d+3)*H_];
    }
    ent_vec[(size_t)be*H_ + j] = ((a0+a1)+(a2+a3)) + b2[j];
}

// ---------------- M[b] = span_w2 @ ent_vec[b]^T (fp64, decode-critical) ----------------
__global__ void k_M(const float* __restrict__ span_w2, const float* __restrict__ ent_vec,
                    float* __restrict__ M){
    int blk = blockIdx.x; int b = blk/32; int dbase = (blk%32)*16;
    int tid = threadIdx.x; int d = dbase + (tid>>4); int e = tid&15;
    const float* ev = ent_vec + ((size_t)b*E_ + e)*H_;
    const float* wr = span_w2 + (size_t)d*H_;
    double p0=0.0, p1=0.0;
    for (int h = 0; h < H_; h += 2){
        p0 += (double)wr[h]*(double)ev[h];
        p1 += (double)wr[h+1]*(double)ev[h+1];
    }
    M[((size_t)b*DFF_ + d)*E_ + e] = (float)(p0+p1);
}

__global__ void k_c(const float* __restrict__ span_b2, const float* __restrict__ ent_vec,
                    float* __restrict__ cvec){
    int i = blockIdx.x*blockDim.x + threadIdx.x;
    if (i >= B_*E_) return;
    const float* ev = ent_vec + (size_t)i*H_;
    double acc = 0.0;
    for (int h = 0; h < H_; h++) acc += (double)span_b2[h]*(double)ev[h];
    cvec[i] = (float)acc;
}

// ---------------- P/Q projection: tiled fp32 GEMM, 64x64 tiles, 2 batches per pass ----------------
//   C[1008 x 1024] = A[1008 x 768] @ Bmat[768 x 1024]
//   cols 0..511: W1[0:768, :], cols 512..1023: W1[768:1536, :]
__global__ void k_pq(const float* __restrict__ wemb, const float* __restrict__ w1,
                     float* __restrict__ PQ, int b0){
    __shared__ float As[16][68];   // [k][row], +4 pad keeps 16B alignment
    __shared__ float Bs[16][68];   // [k][col]
    int bx = blockIdx.x & 15;      // col tile
    int by = blockIdx.x >> 4;      // row tile (0..15)
    int tid = threadIdx.x;
    int tm = tid >> 4, tn = tid & 15;
    const float* A0 = wemb + (size_t)b0*W_*H_;
    int colbase = bx*64;
    const float* Bbase = (colbase < DFF_) ? w1 : (w1 + (size_t)H_*DFF_);
    int bcol0 = (colbase < DFF_) ? colbase : (colbase - DFF_);
    float acc[4][4] = {{0.f}};
    // staging indices
    int ar = tid >> 2, akq = tid & 3;            // A: row, k-quad
    int bkk = tid >> 4, bcq = tid & 15;          // B: k, col-quad
    for (int k0 = 0; k0 < H_; k0 += 16){
        {   // A tile: 64 rows x 16 k, float4 per thread
            int gr = by*64 + ar;
            float4 av;
            if (gr < 1008) av = *(const float4*)(A0 + (size_t)gr*H_ + k0 + akq*4);
            else av = make_float4(0.f,0.f,0.f,0.f);
            As[akq*4+0][ar] = av.x; As[akq*4+1][ar] = av.y;
            As[akq*4+2][ar] = av.z; As[akq*4+3][ar] = av.w;
        }
        {   // B tile: 16 k x 64 cols, float4 per thread
            float4 bv = *(const float4*)(Bbase + (size_t)(k0+bkk)*DFF_ + bcol0 + bcq*4);
            Bs[bkk][bcq*4+0] = bv.x; Bs[bkk][bcq*4+1] = bv.y;
            Bs[bkk][bcq*4+2] = bv.z; Bs[bkk][bcq*4+3] = bv.w;
        }
        __syncthreads();
        #pragma unroll
        for (int kk = 0; kk < 16; kk++){
            float4 a = *(const float4*)&As[kk][tm*4];
            float4 bv = *(const float4*)&Bs[kk][tn*4];
            acc[0][0] += a.x*bv.x; acc[0][1] += a.x*bv.y; acc[0][2] += a.x*bv.z; acc[0][3] += a.x*bv.w;
            acc[1][0] += a.y*bv.x; acc[1][1] += a.y*bv.y; acc[1][2] += a.y*bv.z; acc[1][3] += a.y*bv.w;
            acc[2][0] += a.z*bv.x; acc[2][1] += a.z*bv.y; acc[2][2] += a.z*bv.z; acc[2][3] += a.z*bv.w;
            acc[3][0] += a.w*bv.x; acc[3][1] += a.w*bv.y; acc[3][2] += a.w*bv.z; acc[3][3] += a.w*bv.w;
        }
        __syncthreads();
    }
    #pragma unroll
    for (int r = 0; r < 4; r++){
        int gr = by*64 + tm*4 + r;
        if (gr < 1008){
            float4 ov = make_float4(acc[r][0], acc[r][1], acc[r][2], acc[r][3]);
            *(float4*)(PQ + (size_t)gr*1024 + colbase + tn*4) = ov;
        }
    }
}

// ---------------- logits: one block (256 thr) per (bl, start s); M held in registers ----------------
// Each thread owns (ee = tid&15, d-range [g*32, g*32+32)); the 32 M values it ever
// touches are loaded ONCE into VGPRs from global (same floats, same fp64 accumulation
// order as the previous Msh version -> bit-identical logits). LDS drops 38.4KB -> 6.2KB.
__global__ void k_logits(const float* __restrict__ PQ, const float* __restrict__ Mmat,
                         const float* __restrict__ cvec, const float* __restrict__ span_b1,
                         float* __restrict__ logits, float* __restrict__ outL, int b0){
    __shared__ float Ps[DFF_];
    __shared__ float hid[DFF_];
    __shared__ double red[256];
    __shared__ float csh[E_];
    int blk = blockIdx.x;            // 2*W_ blocks
    int bl = blk / W_; int s = blk - bl*W_;
    int b = b0 + bl;
    int tid = threadIdx.x;
    int ee = tid & 15; int g = tid >> 4;   // 16 groups x 32 d
    float Mreg[32];
    {
        const float* Mp = Mmat + (size_t)b*DFF_*E_ + (size_t)(g*32)*E_ + ee;
        #pragma unroll
        for (int i = 0; i < 32; i++) Mreg[i] = Mp[(size_t)i*E_];
    }
    const float* P = PQ + ((size_t)(bl*W_ + s))*1024;
    for (int d = tid; d < DFF_; d += 256) Ps[d] = P[d] + span_b1[d];
    if (tid < E_) csh[tid] = cvec[b*E_ + tid];
    __syncthreads();
    int nsp = min(12, W_ - s);
    int nbase = rowstart_of(s);
    for (int i = 0; i < nsp; i++){
        int e = s + i;
        const float* Q = PQ + ((size_t)(bl*W_ + e))*1024 + DFF_;
        for (int d = tid; d < DFF_; d += 256){
            float h = Ps[d] + Q[d];
            hid[d] = h > 0.f ? h : 0.01f*h;
        }
        __syncthreads();
        {
            double acc = 0.0;
            int d0 = g*32;
            #pragma unroll
            for (int k = 0; k < 32; k++) acc += (double)hid[d0+k]*(double)Mreg[k];
            red[tid] = acc;
        }
        __syncthreads();
        if (tid < E_){
            double t = 0.0;
            for (int gg = 0; gg < 16; gg++) t += red[gg*16 + tid];
            float lg = (float)(t + (double)csh[tid]);
            size_t oi = ((size_t)b*N_ + nbase + i)*E_ + tid;
            logits[oi] = lg;
            outL[oi] = lg;
        }
        __syncthreads();
    }
}

// ---------------- per-span best candidate (exact greedy-equivalence reduction) ----------------
// Packs span start (bits 48..56) and len-1 (bits 57..60) into the candidate word
// (sort keys are bits 24..47, so order/stability is unaffected).
// Also records the per-word width-1 candidate key (low 48 bits) for dominance pruning.
__global__ void k_spanbest(const float* __restrict__ logits,
                           const int* __restrict__ starts, const int* __restrict__ ends,
                           u64* __restrict__ candS, u64* __restrict__ w1tab){
    int idx = blockIdx.x*256 + threadIdx.x;      // over B_*N_
    if (idx >= B_*N_) return;
    int b = idx / N_; int n = idx - b*N_;
    const float* lg = logits + (size_t)b*NE_ + (size_t)n*16;
    u64 best = ~0ull;
    for (int e = 0; e < 16; e++){
        float prob = 1.0f/(1.0f + expf(-lg[e]));
        if (prob > 0.5f){
            u32 key24 = (~__float_as_uint(prob)) & 0xFFFFFFu;
            u64 pk = ((u64)key24 << 24) | (u64)(u32)(n*16 + e);
            best = best < pk ? best : pk;
        }
    }
    int s = starts[n], e2 = ends[n];
    int len = e2 - s + 1;
    u64 packed = best;
    if (best != ~0ull)
        packed = best | ((u64)(u32)s << 48) | ((u64)(u32)(len-1) << 57);
    candS[idx] = packed;
    if (len == 1) w1tab[b*W_ + s] = best;   // low-48 key; ~0ull if no candidate
}

// ---------------- stable compaction (span order) + width-1 dominance pruning ----------------
// A candidate [s,e] ranked after the width-1 candidate [w,w] for some w in [s,e]
// is guaranteed-rejected by the greedy decode (after [w,w] is processed, w is covered
// whatever happened before). Dropping it changes no decision. Width-1 spans compare
// equal to themselves and are never pruned.
__global__ void k_compact2(const u64* __restrict__ candS, const u64* __restrict__ w1tab,
                           u64* __restrict__ candA, int* __restrict__ cnt){
    __shared__ u64 w1s[W_];
    __shared__ u32 wt[4];
    __shared__ u32 wpre[5];
    __shared__ u32 sbase;
    int b = blockIdx.x; int tid = threadIdx.x;
    int lane = tid&63, wave = tid>>6;
    for (int i = tid; i < W_; i += 256) w1s[i] = w1tab[b*W_ + i];
    if (tid == 0) sbase = 0;
    __syncthreads();
    for (int base = 0; base < N_; base += 256){
        int nidx = base + tid;
        u64 v = (nidx < N_) ? candS[(size_t)b*N_ + nidx] : ~0ull;
        bool f = (v != ~0ull);
        if (f){
            u64 vlow = v & 0xFFFFFFFFFFFFull;
            int s = (int)((v >> 48) & 0x1FFull);
            int len = (int)((v >> 57) & 0xFull) + 1;
            for (int w = s; w < s + len; w++){
                if (w1s[w] < vlow){ f = false; break; }
            }
        }
        u64 bal = __ballot(f);
        if (lane == 0) wt[wave] = (u32)__popcll(bal);
        __syncthreads();
        if (tid == 0){ u32 r = 0; for (int w = 0; w < 4; w++){ wpre[w] = r; r += wt[w]; } wpre[4] = r; }
        __syncthreads();
        if (f){
            u32 rank = (u32)__popcll(bal & ((1ull<<lane) - 1ull));
            candA[(size_t)b*MAXC_ + sbase + wpre[wave] + rank] = v;
        }
        __syncthreads();
        if (tid == 0) sbase += wpre[4];
        __syncthreads();
    }
    if (tid == 0) cnt[b] = (int)sbase;
}

// ---------------- stable LSD radix: 6 x 4-bit over key24 (bits 24..47), single kernel ----------------
__global__ void k_sort(u64* __restrict__ A, u64* __restrict__ Bb, const int* __restrict__ cnt){
    __shared__ u32 hist[16*256];
    __shared__ u32 wtot[4];
    __shared__ u32 woff[4];
    int b = blockIdx.x; int t = threadIdx.x;
    int n = cnt[b];
    u64* buf0 = A  + (size_t)b*MAXC_;
    u64* buf1 = Bb + (size_t)b*MAXC_;
    int chunk = (n + 255) >> 8;
    int lo = t*chunk; int hi = lo + chunk; if (hi > n) hi = n; if (lo > n) lo = n;
    int lane = t & 63, wave = t >> 6;
    for (int p = 0; p < 6; p++){
        u64* ip = (p & 1) ? buf1 : buf0;
        u64* op = (p & 1) ? buf0 : buf1;
        int shift = 24 + 4*p;
        for (int j = t; j < 16*256; j += 256) hist[j] = 0;
        __syncthreads();
        for (int i = lo; i < hi; i++) hist[((int)((ip[i] >> shift) & 15ull))*256 + t]++;
        __syncthreads();
        u32 v[16];
        #pragma unroll
        for (int j = 0; j < 16; j++) v[j] = hist[t*16 + j];
        u32 run = 0;
        #pragma unroll
        for (int j = 0; j < 16; j++){ u32 tmp = v[j]; v[j] = run; run += tmp; }
        u32 inc = run;
        for (int d = 1; d < 64; d <<= 1){ u32 o = __shfl_up(inc, d, 64); if (lane >= d) inc += o; }
        u32 excl = inc - run;
        if (lane == 63) wtot[wave] = inc;
        __syncthreads();
        if (t == 0){ u32 r = 0; for (int w = 0; w < 4; w++){ woff[w] = r; r += wtot[w]; } }
        __syncthreads();
        u32 gbase = woff[wave] + excl;
        #pragma unroll
        for (int j = 0; j < 16; j++) hist[t*16 + j] = gbase + v[j];
        __syncthreads();
        for (int i = lo; i < hi; i++){
            u64 val = ip[i];
            int d = (int)((val >> shift) & 15ull);
            u32 pz = hist[d*256 + t];
            hist[d*256 + t] = pz + 1;
            op[pz] = val;
        }
        __syncthreads();
    }
}

// ---------------- greedy NMS decode: register coverage, packed spans, prefetch ----------------
// Single wave per batch. Coverage (504 bits) replicated in each lane's registers with
// fully-static indexing. A tentative lane is disjoint from coverage by construction,
// so newly-covered bits == span length (no popcount of old state needed). The accept
// chain is: ctz -> one u64 shuffle -> ~25 VALU ops -> ballot. No LDS, no barriers.
__global__ void k_decode(const u64* __restrict__ sorted, const int* __restrict__ cnt,
                         float* __restrict__ outSel){
    int b = blockIdx.x; int lane = threadIdx.x;
    int n = cnt[b];
    const u64* sp = sorted + (size_t)b*MAXC_;
    u64 cov[8];
    #pragma unroll
    for (int k = 0; k < 8; k++) cov[k] = 0ull;
    int covcnt = 0;
    u64 vcur = (lane < n) ? sp[lane] : ~0ull;
    for (int base = 0; base < n; base += 64){
        u64 v = vcur;
        {   // prefetch next chunk; latency hides under the accept loop
            int nb = base + 64 + lane;
            vcur = (nb < n) ? sp[nb] : ~0ull;
        }
        bool has = (base + lane < n);
        int s   = (int)((v >> 48) & 0x1FFull);
        int len = (int)((v >> 57) & 0xFull) + 1;
        u32 c   = (u32)(v & 0xFFFFFFull);
        int w0 = s >> 6, sh0 = s & 63;
        int w1i = (w0 < 7) ? w0 + 1 : 7;
        u64 full = (1ull << len) - 1ull;              // len <= 12
        u64 m0 = has ? (full << sh0) : 0ull;
        u64 m1 = (has && sh0 + len > 64) ? (full >> (64 - sh0)) : 0ull;
        u64 myc0 = 0ull, myc1 = 0ull;
        #pragma unroll
        for (int k = 0; k < 8; k++){
            if (w0  == k) myc0 = cov[k];
            if (w1i == k) myc1 = cov[k];
        }
        bool tent = has && (((myc0 & m0) | (myc1 & m1)) == 0ull);
        u64 bal = __ballot(tent);
        while (bal){
            int j = __builtin_ctzll(bal);
            u64 jv = shfl_u64(v, j);
            int js   = (int)((jv >> 48) & 0x1FFull);
            int jlen = (int)((jv >> 57) & 0xFull) + 1;
            int jw0 = js >> 6, jsh = js & 63;
            int jw1 = (jw0 < 7) ? jw0 + 1 : 7;
            u64 jfull = (1ull << jlen) - 1ull;
            u64 jm0 = jfull << jsh;
            u64 jm1 = (jsh + jlen > 64) ? (jfull >> (64 - jsh)) : 0ull;
            covcnt += jlen;                            // disjoint by construction
            #pragma unroll
            for (int k = 0; k < 8; k++){
                u64 add = 0ull;
                if (jw0 == k) add |= jm0;
                if (jw1 == k && jw1 != jw0) add |= jm1;
                cov[k] |= add;
            }
            u64 a0 = 0ull, a1 = 0ull;
            if (jw0 == w0)  a0 |= jm0;
            if (jw1 == w0  && jw1 != jw0) a0 |= jm1;
            if (jw0 == w1i) a1 |= jm0;
            if (jw1 == w1i && jw1 != jw0) a1 |= jm1;
            myc0 |= a0; myc1 |= a1;
            if (lane == j) outSel[(size_t)BNE_ + (size_t)b*NE_ + (size_t)c] = 1.0f;
            tent = tent && (lane > j) && (((myc0 & m0) | (myc1 & m1)) == 0ull);
            bal = __ballot(tent);
        }
        if (covcnt >= W_) break;
    }
}

extern "C" void kernel_launch(void* const* d_in, const int* in_sizes, int n_in,
                              void* d_out, int out_size, void* d_ws, size_t ws_size,
                              hipStream_t stream){
    const float* hs        = (const float*)d_in[0];
    const float* ent_w1    = (const float*)d_in[1];
    const float* ent_b1    = (const float*)d_in[2];
    const float* ent_w2    = (const float*)d_in[3];
    const float* ent_b2    = (const float*)d_in[4];
    const float* span_w1   = (const float*)d_in[5];
    const float* span_b1   = (const float*)d_in[6];
    const float* span_w2   = (const float*)d_in[7];
    const float* span_b2   = (const float*)d_in[8];
    const int*  text_mask  = (const int*)d_in[9];
    const int*  ent_mask   = (const int*)d_in[10];
    const int*  word_index = (const int*)d_in[11];
    float* out = (float*)d_out;

    // ---- workspace (~20.9 MB peak; candidate buffers overlay dead wemb) ----
    char* wsbase = (char*)d_ws; size_t off = 0;
    auto alloc = [&](size_t bytes)->void*{ void* p = wsbase + off; off = (off + bytes + 255) & ~(size_t)255; return p; };
    char*  region1 = (char*)alloc((size_t)B_*W_*H_*4);    // 12,386,304 B
    float* wemb   = (float*)region1;                       // phase 1
    u64*   candS  = (u64*)region1;                         // phase 2: 382,848 B
    u64*   candA  = (u64*)(region1 + 393216);              // 393,216 B
    u64*   candB  = (u64*)(region1 + 786432);              // 393,216 B
    int*   tok    = (int*)  alloc((size_t)B_*W_*4*4);
    int*   tokc   = (int*)  alloc((size_t)B_*W_*4);
    float* PQ     = (float*)alloc((size_t)2*W_*1024*4);    // 4,128,768 B (2 batches/pass)
    float* logits = (float*)alloc((size_t)BNE_*4);         // 3,062,784 B
    int*   entpos = (int*)  alloc((size_t)B_*E_*4);
    float* hidg   = (float*)alloc((size_t)B_*E_*DFF_*4);   // 262,144 B
    float* entvec = (float*)alloc((size_t)B_*E_*H_*4);
    float* Mmat   = (float*)alloc((size_t)B_*DFF_*E_*4);
    float* cvec   = (float*)alloc((size_t)B_*E_*4);
    int*   starts = (int*)  alloc((size_t)N_*4);
    int*   ends   = (int*)  alloc((size_t)N_*4);
    int*   cntp   = (int*)  alloc((size_t)B_*4);
    u64*   w1tab  = (u64*)  alloc((size_t)B_*W_*8);        // 32,256 B

    hipMemsetAsync((void*)(out + BNE_), 0, (size_t)BNE_*4, stream);   // selected := 0.0f
    hipMemsetAsync(tokc, 0, (size_t)B_*W_*4, stream);

    k_tables<<<8,64,0,stream>>>(starts, ends);
    k_toklist<<<(B_*L_+255)/256,256,0,stream>>>(text_mask, word_index, tok, tokc);
    k_toksort<<<(B_*W_+255)/256,256,0,stream>>>(tok, tokc);
    k_pool<<<(B_*W_*H_+255)/256,256,0,stream>>>(hs, tok, tokc, wemb);
    k_entpos<<<B_,64,0,stream>>>(ent_mask, entpos);
    k_ent1<<<B_*E_*2,256,0,stream>>>(hs, entpos, ent_w1, ent_b1, hidg);
    k_ent2<<<B_*E_*3,256,0,stream>>>(hidg, ent_w2, ent_b2, entvec);
    k_M<<<B_*32,256,0,stream>>>(span_w2, entvec, Mmat);
    k_c<<<(B_*E_+63)/64,64,0,stream>>>(span_b2, entvec, cvec);
    for (int b0 = 0; b0 < B_; b0 += 2){
        k_pq<<<256,256,0,stream>>>(wemb, span_w1, PQ, b0);
        k_logits<<<2*W_,256,0,stream>>>(PQ, Mmat, cvec, span_b1, logits, out, b0);
    }
    // wemb dead from here; region1 hosts candS/candA/candB
    k_spanbest<<<(B_*N_+255)/256,256,0,stream>>>(logits, starts, ends, candS, w1tab);
    k_compact2<<<B_,256,0,stream>>>(candS, w1tab, candA, cntp);
    k_sort<<<B_,256,0,stream>>>(candA, candB, cntp);
    k_decode<<<B_,64,0,stream>>>(candA, cntp, out);
}

// Round 2
// 587.151 us; speedup vs baseline: 1.1788x; 1.0132x over previous
//
#include <hip/hip_runtime.h>
#include <hip/hip_bf16.h>
#include <stdint.h>

#define B_ 8
#define L_ 1024
#define H_ 768
#define E_ 16
#define W_ 504
#define DFF_ 512
#define N_ 5982
#define NE_ (N_*E_)    // 95712 candidates per batch
#define BNE_ (B_*NE_)  // 765696
#define MAXC_ 6144     // padded per-batch candidate capacity (>= N_)
#define MAXK48 0x0000FFFFFFFFFFFFull

typedef unsigned long long u64;
typedef unsigned int u32;

__device__ __forceinline__ int rowstart_of(int s){
    int s0 = W_ - 11; // 493
    if (s <= s0) return 12*s;
    int t = s - s0;
    return 12*s0 + t*11 - (t*(t-1))/2;
}

// ---------------- span tables ----------------
__global__ void k_tables(int* starts, int* ends){
    int s = blockIdx.x*64 + threadIdx.x;
    if (s >= W_) return;
    int rs = rowstart_of(s);
    int cnt = min(12, W_ - s);
    for (int i = 0; i < cnt; i++){ starts[rs+i] = s; ends[rs+i] = s+i; }
}

// ---------------- token lists: parallel build + deterministic per-word sort ----------------
__global__ void k_toklist(const int* __restrict__ tm, const int* __restrict__ wi,
                          int* __restrict__ tok, int* __restrict__ tokc){
    int i = blockIdx.x*256 + threadIdx.x;
    if (i >= B_*L_) return;
    int w = wi[i];
    if (tm[i] == 1 && w >= 0 && w < W_){
        int b = i / L_;
        int bw = b*W_ + w;
        int pos = atomicAdd(&tokc[bw], 1);
        if (pos < 4) tok[bw*4 + pos] = i - b*L_;
    }
}

__global__ void k_toksort(int* __restrict__ tok, const int* __restrict__ tokc){
    int bw = blockIdx.x*256 + threadIdx.x;
    if (bw >= B_*W_) return;
    int c = min(tokc[bw], 4);
    int v[4];
    for (int k = 0; k < c; k++) v[k] = tok[bw*4 + k];
    for (int a = 1; a < c; a++){ int x = v[a]; int j = a-1; while (j >= 0 && v[j] > x){ v[j+1] = v[j]; j--; } v[j+1] = x; }
    for (int k = 0; k < c; k++) tok[bw*4 + k] = v[k];
}

// ---------------- word mean pooling (gather, deterministic) ----------------
__global__ void k_pool(const float* __restrict__ hs,
                       const int* __restrict__ tok, const int* __restrict__ tokc,
                       float* __restrict__ wemb){
    int idx = blockIdx.x*256 + threadIdx.x;      // over B*W*H
    if (idx >= B_*W_*H_) return;
    int h = idx % H_; int bw = idx / H_; int b = bw / W_;
    int c = tokc[bw]; int cc = min(c, 4);
    double s = 0.0;
    for (int k = 0; k < cc; k++){
        int l = tok[bw*4 + k];
        s += (double)hs[((size_t)(b*L_ + l))*H_ + h];
    }
    float denom = (float)max(c, 1);
    wemb[idx] = (float)(s / (double)denom);
}

// ---------------- entity positions: literal stable scan ----------------
__global__ void k_entpos(const int* __restrict__ ent_mask, int* __restrict__ ent_pos){
    int b = blockIdx.x;
    if (threadIdx.x != 0) return;
    int c = 0;
    for (int l = 0; l < L_ && c < E_; l++) if (ent_mask[b*L_ + l] == 1) ent_pos[b*E_ + c++] = l;
    for (int l = 0; l < L_ && c < E_; l++) if (ent_mask[b*L_ + l] != 1) ent_pos[b*E_ + c++] = l;
}

// ---------------- entity MLP layer 1 ----------------
__global__ void k_ent1(const float* __restrict__ hs, const int* __restrict__ ent_pos,
                       const float* __restrict__ w1, const float* __restrict__ b1,
                       float* __restrict__ hidg){
    __shared__ float x[H_];
    int blk = blockIdx.x;            // 256 blocks: be*2 + half
    int be = blk >> 1; int half = blk & 1;
    int b = be >> 4;
    int tid = threadIdx.x;
    int pos = ent_pos[be];
    const float* xp = hs + ((size_t)b*L_ + pos)*H_;
    for (int j = tid; j < H_; j += 256) x[j] = xp[j];
    __syncthreads();
    int d = half*256 + tid;
    float a0=0.f,a1=0.f,a2=0.f,a3=0.f;
    const float* wp = w1 + d;
    #pragma unroll 4
    for (int h = 0; h < H_; h += 4){
        a0 += x[h+0]*wp[(size_t)(h+0)*DFF_];
        a1 += x[h+1]*wp[(size_t)(h+1)*DFF_];
        a2 += x[h+2]*wp[(size_t)(h+2)*DFF_];
        a3 += x[h+3]*wp[(size_t)(h+3)*DFF_];
    }
    float acc = ((a0+a1)+(a2+a3)) + b1[d];
    hidg[(size_t)be*DFF_ + d] = acc > 0.f ? acc : 0.01f*acc;
}

// ---------------- entity MLP layer 2 ----------------
__global__ void k_ent2(const float* __restrict__ hidg,
                       const float* __restrict__ w2, const float* __restrict__ b2,
                       float* __restrict__ ent_vec){
    __shared__ float hsd[DFF_];
    int blk = blockIdx.x;            // 384 blocks: be*3 + third
    int be = blk / 3; int third = blk % 3;
    int tid = threadIdx.x;
    const float* hp = hidg + (size_t)be*DFF_;
    for (int j = tid; j < DFF_; j += 256) hsd[j] = hp[j];
    __syncthreads();
    int j = third*256 + tid;
    float a0=0.f,a1=0.f,a2=0.f,a3=0.f;
    const float* wp = w2 + j;
    #pragma unroll 4
    for (int d = 0; d < DFF_; d += 4){
        a0 += hsd[d+0]*wp[(size_t)(d+0)*H_];
        a1 += hsd[d+1]*wp[(size_t)(d+1)*H_];
        a2 += hsd[d+2]*wp[(size_t)(d+2)*H_];
        a3 += hsd[d+3]*wp[(size_t)(d+3)*H_];
    }
    ent_vec[(size_t)be*H_ + j] = ((a0+a1)+(a2+a3)) + b2[j];
}

// ---------------- M[b] = span_w2 @ ent_vec[b]^T (fp64, decode-critical) ----------------
__global__ void k_M(const float* __restrict__ span_w2, const float* __restrict__ ent_vec,
                    float* __restrict__ M){
    int blk = blockIdx.x; int b = blk/32; int dbase = (blk%32)*16;
    int tid = threadIdx.x; int d = dbase + (tid>>4); int e = tid&15;
    const float* ev = ent_vec + ((size_t)b*E_ + e)*H_;
    const float* wr = span_w2 + (size_t)d*H_;
    double p0=0.0, p1=0.0;
    for (int h = 0; h < H_; h += 2){
        p0 += (double)wr[h]*(double)ev[h];
        p1 += (double)wr[h+1]*(double)ev[h+1];
    }
    M[((size_t)b*DFF_ + d)*E_ + e] = (float)(p0+p1);
}

__global__ void k_c(const float* __restrict__ span_b2, const float* __restrict__ ent_vec,
                    float* __restrict__ cvec){
    int i = blockIdx.x*blockDim.x + threadIdx.x;
    if (i >= B_*E_) return;
    const float* ev = ent_vec + (size_t)i*H_;
    double acc = 0.0;
    for (int h = 0; h < H_; h++) acc += (double)span_b2[h]*(double)ev[h];
    cvec[i] = (float)acc;
}

// ---------------- P/Q projection: tiled fp32 GEMM, 64x64 tiles, 2 batches per pass ----------------
__global__ void k_pq(const float* __restrict__ wemb, const float* __restrict__ w1,
                     float* __restrict__ PQ, int b0){
    __shared__ float As[16][68];   // [k][row], +4 pad keeps 16B alignment
    __shared__ float Bs[16][68];   // [k][col]
    int bx = blockIdx.x & 15;      // col tile
    int by = blockIdx.x >> 4;      // row tile (0..15)
    int tid = threadIdx.x;
    int tm = tid >> 4, tn = tid & 15;
    const float* A0 = wemb + (size_t)b0*W_*H_;
    int colbase = bx*64;
    const float* Bbase = (colbase < DFF_) ? w1 : (w1 + (size_t)H_*DFF_);
    int bcol0 = (colbase < DFF_) ? colbase : (colbase - DFF_);
    float acc[4][4] = {{0.f}};
    int ar = tid >> 2, akq = tid & 3;            // A: row, k-quad
    int bkk = tid >> 4, bcq = tid & 15;          // B: k, col-quad
    for (int k0 = 0; k0 < H_; k0 += 16){
        {
            int gr = by*64 + ar;
            float4 av;
            if (gr < 1008) av = *(const float4*)(A0 + (size_t)gr*H_ + k0 + akq*4);
            else av = make_float4(0.f,0.f,0.f,0.f);
            As[akq*4+0][ar] = av.x; As[akq*4+1][ar] = av.y;
            As[akq*4+2][ar] = av.z; As[akq*4+3][ar] = av.w;
        }
        {
            float4 bv = *(const float4*)(Bbase + (size_t)(k0+bkk)*DFF_ + bcol0 + bcq*4);
            Bs[bkk][bcq*4+0] = bv.x; Bs[bkk][bcq*4+1] = bv.y;
            Bs[bkk][bcq*4+2] = bv.z; Bs[bkk][bcq*4+3] = bv.w;
        }
        __syncthreads();
        #pragma unroll
        for (int kk = 0; kk < 16; kk++){
            float4 a = *(const float4*)&As[kk][tm*4];
            float4 bv = *(const float4*)&Bs[kk][tn*4];
            acc[0][0] += a.x*bv.x; acc[0][1] += a.x*bv.y; acc[0][2] += a.x*bv.z; acc[0][3] += a.x*bv.w;
            acc[1][0] += a.y*bv.x; acc[1][1] += a.y*bv.y; acc[1][2] += a.y*bv.z; acc[1][3] += a.y*bv.w;
            acc[2][0] += a.z*bv.x; acc[2][1] += a.z*bv.y; acc[2][2] += a.z*bv.z; acc[2][3] += a.z*bv.w;
            acc[3][0] += a.w*bv.x; acc[3][1] += a.w*bv.y; acc[3][2] += a.w*bv.z; acc[3][3] += a.w*bv.w;
        }
        __syncthreads();
    }
    #pragma unroll
    for (int r = 0; r < 4; r++){
        int gr = by*64 + tm*4 + r;
        if (gr < 1008){
            float4 ov = make_float4(acc[r][0], acc[r][1], acc[r][2], acc[r][3]);
            *(float4*)(PQ + (size_t)gr*1024 + colbase + tn*4) = ov;
        }
    }
}

// ---------------- logits: one block (256 thr) per (bl, start s); M held in registers ----------------
__global__ void k_logits(const float* __restrict__ PQ, const float* __restrict__ Mmat,
                         const float* __restrict__ cvec, const float* __restrict__ span_b1,
                         float* __restrict__ logits, float* __restrict__ outL, int b0){
    __shared__ float Ps[DFF_];
    __shared__ float hid[DFF_];
    __shared__ double red[256];
    __shared__ float csh[E_];
    int blk = blockIdx.x;            // 2*W_ blocks
    int bl = blk / W_; int s = blk - bl*W_;
    int b = b0 + bl;
    int tid = threadIdx.x;
    int ee = tid & 15; int g = tid >> 4;   // 16 groups x 32 d
    float Mreg[32];
    {
        const float* Mp = Mmat + (size_t)b*DFF_*E_ + (size_t)(g*32)*E_ + ee;
        #pragma unroll
        for (int i = 0; i < 32; i++) Mreg[i] = Mp[(size_t)i*E_];
    }
    const float* P = PQ + ((size_t)(bl*W_ + s))*1024;
    for (int d = tid; d < DFF_; d += 256) Ps[d] = P[d] + span_b1[d];
    if (tid < E_) csh[tid] = cvec[b*E_ + tid];
    __syncthreads();
    int nsp = min(12, W_ - s);
    int nbase = rowstart_of(s);
    for (int i = 0; i < nsp; i++){
        int e = s + i;
        const float* Q = PQ + ((size_t)(bl*W_ + e))*1024 + DFF_;
        for (int d = tid; d < DFF_; d += 256){
            float h = Ps[d] + Q[d];
            hid[d] = h > 0.f ? h : 0.01f*h;
        }
        __syncthreads();
        {
            double acc = 0.0;
            int d0 = g*32;
            #pragma unroll
            for (int k = 0; k < 32; k++) acc += (double)hid[d0+k]*(double)Mreg[k];
            red[tid] = acc;
        }
        __syncthreads();
        if (tid < E_){
            double t = 0.0;
            for (int gg = 0; gg < 16; gg++) t += red[gg*16 + tid];
            float lg = (float)(t + (double)csh[tid]);
            size_t oi = ((size_t)b*N_ + nbase + i)*E_ + tid;
            logits[oi] = lg;
            outL[oi] = lg;
        }
        __syncthreads();
    }
}

// ---------------- per-span best candidate, packed with (s, len-1) in bits 48..60 ----------------
__global__ void k_spanbest(const float* __restrict__ logits,
                           const int* __restrict__ starts, const int* __restrict__ ends,
                           u64* __restrict__ candS){
    int idx = blockIdx.x*256 + threadIdx.x;      // over B_*N_
    if (idx >= B_*N_) return;
    int b = idx / N_; int n = idx - b*N_;
    const float* lg = logits + (size_t)b*NE_ + (size_t)n*16;
    u64 best = ~0ull;
    for (int e = 0; e < 16; e++){
        float prob = 1.0f/(1.0f + expf(-lg[e]));
        if (prob > 0.5f){
            u32 key24 = (~__float_as_uint(prob)) & 0xFFFFFFu;
            u64 pk = ((u64)key24 << 24) | (u64)(u32)(n*16 + e);
            best = best < pk ? best : pk;
        }
    }
    int s = starts[n], e2 = ends[n];
    int len = e2 - s + 1;
    u64 packed = best;
    if (best != ~0ull)
        packed = best | ((u64)(u32)s << 48) | ((u64)(u32)(len-1) << 57);
    candS[idx] = packed;
}

// ---------------- scalar-replay greedy decode (single wave, wave-uniform SALU loop) ----------------
// Ballot once per 64-chunk; iterate tentative bits in a uniform scalar loop:
// j = ctz(bal); candidate j fetched via v_readlane (-> SGPRs); coverage kept in 8
// statically-indexed u64s (uniform -> s_cselect mux); test+update all scalar.
// Decisions replayed in exact rank order vs live coverage => identical to reference greedy.
__device__ __forceinline__ void decode_wave(const u64* __restrict__ sp, int n,
                                            float* __restrict__ outSel, int b){
    int lane = threadIdx.x;   // 0..63
    u64 scov[8];
    #pragma unroll
    for (int k = 0; k < 8; k++) scov[k] = 0ull;
    int covcnt = 0;
    u64 vcur = (lane < n) ? sp[lane] : ~0ull;
    for (int base = 0; base < n; base += 64){
        u64 v = vcur;
        {   // prefetch next chunk
            int nb = base + 64 + lane;
            vcur = (nb < n) ? sp[nb] : ~0ull;
        }
        bool has = (base + lane < n);
        int s   = (int)((v >> 48) & 0x1FFull);
        int len = (int)((v >> 57) & 0xFull) + 1;
        u32 c   = (u32)(v & 0xFFFFFFull);
        int w0 = s >> 6, sh0 = s & 63;
        int w1i = (w0 < 7) ? w0 + 1 : 7;
        u64 full = (1ull << len) - 1ull;
        u64 m0 = has ? (full << sh0) : 0ull;
        u64 m1 = (has && sh0 + len > 64) ? (full >> (64 - sh0)) : 0ull;
        u64 myc0 = 0ull, myc1 = 0ull;
        #pragma unroll
        for (int k = 0; k < 8; k++){
            if (w0  == k) myc0 = scov[k];
            if (w1i == k) myc1 = scov[k];
        }
        bool tent = has && (((myc0 & m0) | (myc1 & m1)) == 0ull);
        u64 bal = __ballot(tent);
        u32 vlo = (u32)v, vhi = (u32)(v >> 32);
        u64 acc = 0ull;
        while (bal){
            int j = (int)__builtin_ctzll(bal);
            bal &= bal - 1ull;
#if __has_builtin(__builtin_amdgcn_readlane)
            u32 jlo = (u32)__builtin_amdgcn_readlane((int)vlo, j);
            u32 jhi = (u32)__builtin_amdgcn_readlane((int)vhi, j);
#else
            u32 jlo = (u32)__shfl((int)vlo, j, 64);
            u32 jhi = (u32)__shfl((int)vhi, j, 64);
#endif
            u64 jv = ((u64)jhi << 32) | (u64)jlo;
            int js   = (int)((jv >> 48) & 0x1FFull);
            int jlen = (int)((jv >> 57) & 0xFull) + 1;
            int jw0 = js >> 6, jsh = js & 63;
            int jw1 = (jw0 < 7) ? jw0 + 1 : 7;
            u64 jfull = (1ull << jlen) - 1ull;
            u64 jm0 = jfull << jsh;
            u64 jm1 = (jsh + jlen > 64) ? (jfull >> (64 - jsh)) : 0ull;
            u64 c0 = 0ull, c1 = 0ull;
            #pragma unroll
            for (int k = 0; k < 8; k++){
                if (jw0 == k) c0 = scov[k];
                if (jw1 == k) c1 = scov[k];
            }
            bool ok = (((c0 & jm0) | (c1 & jm1)) == 0ull);
            u64 okm = ok ? ~0ull : 0ull;
            #pragma unroll
            for (int k = 0; k < 8; k++){
                u64 add = 0ull;
                if (jw0 == k) add |= jm0;
                if (jw1 == k) add |= jm1;   // jm1 nonzero only when crossing => jw1 != jw0
                scov[k] |= (add & okm);
            }
            covcnt += ok ? jlen : 0;
            acc |= (okm & (1ull << j));
        }
        if (((acc >> lane) & 1ull) != 0ull)
            outSel[(size_t)BNE_ + (size_t)b*NE_ + (size_t)c] = 1.0f;
        if (covcnt >= W_) break;
    }
}

// ---------------- fused tail: nested-dominance DP -> compact -> radix sort -> decode ----------------
// One block per batch. Nested dominance (exact): a candidate whose span strictly contains
// an earlier-ranked candidate's span is always rejected by the greedy decode (if the inner
// accepts, it covers part of the outer; if it rejects, the blocking word still blocks the
// outer). DP: M_l[s] = min key over spans within [s, s+l-1]; prune (s,l) iff
// min(M_{l-1}[s], M_{l-1}[s+1]) < key(s,l). Keys unique (flat id in low bits) => strict.
__global__ void k_tail(u64* __restrict__ candS, u64* __restrict__ candA, u64* __restrict__ candB,
                       float* __restrict__ outSel){
    __shared__ u64 Ma[512];
    __shared__ u64 Mb[512];
    __shared__ u32 hist[16*256];
    __shared__ u32 wt[4];
    __shared__ u32 wpre[5];
    __shared__ u32 sbase;
    __shared__ u32 wtot[4];
    __shared__ u32 woff[4];
    __shared__ int ncand;
    int b = blockIdx.x; int tid = threadIdx.x;
    int lane = tid & 63, wave = tid >> 6;
    u64* cS = candS + (size_t)b*N_;

    // ---- Phase A: nested-dominance DP (11 rounds) ----
    for (int s = tid; s < 512; s += 256)
        Ma[s] = (s < W_) ? (cS[rowstart_of(s)] & MAXK48) : MAXK48;
    if (tid == 0) sbase = 0;
    __syncthreads();
    u64* Mcur = Ma; u64* Mnext = Mb;
    for (int l = 2; l <= 12; l++){
        #pragma unroll
        for (int q = 0; q < 2; q++){
            int s = tid + q*256;          // 0..511
            u64 key = MAXK48; int idx = -1;
            if (s + l <= W_){ idx = rowstart_of(s) + (l-1); key = cS[idx] & MAXK48; }
            u64 a = Mcur[s];
            u64 bb = (s + 1 < 512) ? Mcur[s+1] : MAXK48;
            u64 dom = a < bb ? a : bb;
            if (idx >= 0 && dom < key) cS[idx] = ~0ull;      // pruned
            Mnext[s] = dom < key ? dom : key;
        }
        __syncthreads();
        u64* t = Mcur; Mcur = Mnext; Mnext = t;
    }

    // ---- Phase B: stable compaction (span order) ----
    for (int base = 0; base < N_; base += 256){
        int nidx = base + tid;
        u64 v = (nidx < N_) ? cS[nidx] : ~0ull;
        bool f = (v != ~0ull);
        u64 bal = __ballot(f);
        if (lane == 0) wt[wave] = (u32)__popcll(bal);
        __syncthreads();
        if (tid == 0){ u32 r = 0; for (int w = 0; w < 4; w++){ wpre[w] = r; r += wt[w]; } wpre[4] = r; }
        __syncthreads();
        if (f){
            u32 rank = (u32)__popcll(bal & ((1ull<<lane) - 1ull));
            candA[(size_t)b*MAXC_ + sbase + wpre[wave] + rank] = v;
        }
        __syncthreads();
        if (tid == 0) sbase += wpre[4];
        __syncthreads();
    }
    if (tid == 0) ncand = (int)sbase;
    __syncthreads();
    int n = ncand;

    // ---- Phase C: stable LSD radix, 6 x 4-bit over key24 (bits 24..47) ----
    {
        u64* buf0 = candA + (size_t)b*MAXC_;
        u64* buf1 = candB + (size_t)b*MAXC_;
        int chunk = (n + 255) >> 8;
        int lo = tid*chunk; int hi = lo + chunk; if (hi > n) hi = n; if (lo > n) lo = n;
        for (int p = 0; p < 6; p++){
            u64* ip = (p & 1) ? buf1 : buf0;
            u64* op = (p & 1) ? buf0 : buf1;
            int shift = 24 + 4*p;
            for (int j = tid; j < 16*256; j += 256) hist[j] = 0;
            __syncthreads();
            for (int i = lo; i < hi; i++) hist[((int)((ip[i] >> shift) & 15ull))*256 + tid]++;
            __syncthreads();
            u32 v[16];
            #pragma unroll
            for (int j = 0; j < 16; j++) v[j] = hist[tid*16 + j];
            u32 run = 0;
            #pragma unroll
            for (int j = 0; j < 16; j++){ u32 tmp = v[j]; v[j] = run; run += tmp; }
            u32 inc = run;
            for (int d = 1; d < 64; d <<= 1){ u32 o = __shfl_up(inc, d, 64); if (lane >= d) inc += o; }
            u32 excl = inc - run;
            if (lane == 63) wtot[wave] = inc;
            __syncthreads();
            if (tid == 0){ u32 r = 0; for (int w = 0; w < 4; w++){ woff[w] = r; r += wtot[w]; } }
            __syncthreads();
            u32 gbase = woff[wave] + excl;
            #pragma unroll
            for (int j = 0; j < 16; j++) hist[tid*16 + j] = gbase + v[j];
            __syncthreads();
            for (int i = lo; i < hi; i++){
                u64 val = ip[i];
                int d = (int)((val >> shift) & 15ull);
                u32 pz = hist[d*256 + tid];
                hist[d*256 + tid] = pz + 1;
                op[pz] = val;
            }
            __syncthreads();
        }
    }

    // ---- Phase D: decode on wave 0 (no barriers past this point) ----
    if (wave == 0)
        decode_wave(candA + (size_t)b*MAXC_, n, outSel, b);
}

extern "C" void kernel_launch(void* const* d_in, const int* in_sizes, int n_in,
                              void* d_out, int out_size, void* d_ws, size_t ws_size,
                              hipStream_t stream){
    const float* hs        = (const float*)d_in[0];
    const float* ent_w1    = (const float*)d_in[1];
    const float* ent_b1    = (const float*)d_in[2];
    const float* ent_w2    = (const float*)d_in[3];
    const float* ent_b2    = (const float*)d_in[4];
    const float* span_w1   = (const float*)d_in[5];
    const float* span_b1   = (const float*)d_in[6];
    const float* span_w2   = (const float*)d_in[7];
    const float* span_b2   = (const float*)d_in[8];
    const int*  text_mask  = (const int*)d_in[9];
    const int*  ent_mask   = (const int*)d_in[10];
    const int*  word_index = (const int*)d_in[11];
    float* out = (float*)d_out;

    // ---- workspace (~20.9 MB peak; candidate buffers overlay dead wemb) ----
    char* wsbase = (char*)d_ws; size_t off = 0;
    auto alloc = [&](size_t bytes)->void*{ void* p = wsbase + off; off = (off + bytes + 255) & ~(size_t)255; return p; };
    char*  region1 = (char*)alloc((size_t)B_*W_*H_*4);    // 12,386,304 B
    float* wemb   = (float*)region1;                       // phase 1
    u64*   candS  = (u64*)region1;                         // phase 2: 382,848 B
    u64*   candA  = (u64*)(region1 + 393216);              // 393,216 B
    u64*   candB  = (u64*)(region1 + 786432);              // 393,216 B
    int*   tok    = (int*)  alloc((size_t)B_*W_*4*4);
    int*   tokc   = (int*)  alloc((size_t)B_*W_*4);
    float* PQ     = (float*)alloc((size_t)2*W_*1024*4);    // 4,128,768 B (2 batches/pass)
    float* logits = (float*)alloc((size_t)BNE_*4);         // 3,062,784 B
    int*   entpos = (int*)  alloc((size_t)B_*E_*4);
    float* hidg   = (float*)alloc((size_t)B_*E_*DFF_*4);   // 262,144 B
    float* entvec = (float*)alloc((size_t)B_*E_*H_*4);
    float* Mmat   = (float*)alloc((size_t)B_*DFF_*E_*4);
    float* cvec   = (float*)alloc((size_t)B_*E_*4);
    int*   starts = (int*)  alloc((size_t)N_*4);
    int*   ends   = (int*)  alloc((size_t)N_*4);

    hipMemsetAsync((void*)(out + BNE_), 0, (size_t)BNE_*4, stream);   // selected := 0.0f
    hipMemsetAsync(tokc, 0, (size_t)B_*W_*4, stream);

    k_tables<<<8,64,0,stream>>>(starts, ends);
    k_toklist<<<(B_*L_+255)/256,256,0,stream>>>(text_mask, word_index, tok, tokc);
    k_toksort<<<(B_*W_+255)/256,256,0,stream>>>(tok, tokc);
    k_pool<<<(B_*W_*H_+255)/256,256,0,stream>>>(hs, tok, tokc, wemb);
    k_entpos<<<B_,64,0,stream>>>(ent_mask, entpos);
    k_ent1<<<B_*E_*2,256,0,stream>>>(hs, entpos, ent_w1, ent_b1, hidg);
    k_ent2<<<B_*E_*3,256,0,stream>>>(hidg, ent_w2, ent_b2, entvec);
    k_M<<<B_*32,256,0,stream>>>(span_w2, entvec, Mmat);
    k_c<<<(B_*E_+63)/64,64,0,stream>>>(span_b2, entvec, cvec);
    for (int b0 = 0; b0 < B_; b0 += 2){
        k_pq<<<256,256,0,stream>>>(wemb, span_w1, PQ, b0);
        k_logits<<<2*W_,256,0,stream>>>(PQ, Mmat, cvec, span_b1, logits, out, b0);
    }
    // wemb dead from here; region1 hosts candS/candA/candB
    k_spanbest<<<(B_*N_+255)/256,256,0,stream>>>(logits, starts, ends, candS);
    k_tail<<<B_,256,0,stream>>>(candS, candA, candB, out);
}